// Round 10
// baseline (123.925 us; speedup 1.0000x reference)
//
#include <hip/hip_runtime.h>
#include <hip/hip_bf16.h>
#include <stdint.h>

// Problem constants
#define NB 2
#define NS 2048
#define NE 1024
#define NH 16
#define ND 64
#define NTS 16  // K-tiles per split (NS/64/2)

typedef __attribute__((ext_vector_type(4))) float f32x4;
typedef __attribute__((ext_vector_type(8))) float f32x8;
typedef __attribute__((ext_vector_type(16))) float f32x16;
typedef __attribute__((ext_vector_type(8))) short s16x8;
typedef __attribute__((ext_vector_type(4))) unsigned short u16x4;
typedef __attribute__((ext_vector_type(2))) unsigned int uint2v;

__device__ __forceinline__ unsigned short f2bf(float f) {
  union { float f; unsigned int i; } u; u.f = f;
  unsigned int r = u.i + 0x7FFFu + ((u.i >> 16) & 1u);  // RNE
  return (unsigned short)(r >> 16);
}
__device__ __forceinline__ float bf2f(unsigned short u) {
  union { unsigned int i; float f; } x; x.i = ((unsigned int)u) << 16; return x.f;
}

__device__ __forceinline__ unsigned cvtpk_bf16(float lo, float hi) {
  unsigned r;
  asm("v_cvt_pk_bf16_f32 %0, %1, %2" : "=v"(r) : "v"(lo), "v"(hi));
  return r;
}

__device__ __forceinline__ void gload_lds16(const void* g, void* l) {
  __builtin_amdgcn_global_load_lds(
      (const __attribute__((address_space(1))) uint32_t*)g,
      (__attribute__((address_space(3))) uint32_t*)l, 16, 0, 0);
}

__device__ __forceinline__ f32x4 mfma16(s16x8 a, s16x8 b, f32x4 c) {
  return __builtin_amdgcn_mfma_f32_16x16x32_bf16(a, b, c, 0, 0, 0);
}
__device__ __forceinline__ f32x16 mfma32(s16x8 a, s16x8 b, f32x16 c) {
  return __builtin_amdgcn_mfma_f32_32x32x16_bf16(a, b, c, 0, 0, 0);
}

// ---------------- fused prologue: f32->bf16 converts + mask pack (1 launch) ----------------
// grid 3088 x 256: [0,2048) X-converts (q,k); [2048,3072) W-converts; [3072,3088) mask.
__global__ void prep(const float* __restrict__ xq, const float* __restrict__ xk,
                     unsigned short* __restrict__ dq, unsigned short* __restrict__ dk,
                     const float* __restrict__ w0, const float* __restrict__ w1,
                     const float* __restrict__ w2, const float* __restrict__ w3,
                     unsigned short* __restrict__ e0, unsigned short* __restrict__ e1,
                     unsigned short* __restrict__ e2, unsigned short* __restrict__ e3,
                     const int* __restrict__ mask, unsigned long long* __restrict__ bm) {
  const int bid = blockIdx.x, t = threadIdx.x;
  if (bid < 2048) {
    const float* s = (bid < 1024) ? xq : xk;
    unsigned short* d = (bid < 1024) ? dq : dk;
    int i = (bid & 1023) * 256 + t;
    const int n4 = NB * NS * NE / 4, stride = 1024 * 256;
    for (; i < n4; i += stride) {
      float4 v = ((const float4*)s)[i];
      u16x4 o;
      o.x = f2bf(v.x); o.y = f2bf(v.y); o.z = f2bf(v.z); o.w = f2bf(v.w);
      ((u16x4*)d)[i] = o;
    }
  } else if (bid < 3072) {
    int seg = (bid - 2048) >> 8;
    const float* s; unsigned short* d;
    switch (seg) {
      case 0: s = w0; d = e0; break;
      case 1: s = w1; d = e1; break;
      case 2: s = w2; d = e2; break;
      default: s = w3; d = e3; break;
    }
    int i = ((bid - 2048) & 255) * 256 + t;
    const int n4 = NE * NE / 4, stride = 256 * 256;
    for (; i < n4; i += stride) {
      float4 v = ((const float4*)s)[i];
      u16x4 o;
      o.x = f2bf(v.x); o.y = f2bf(v.y); o.z = f2bf(v.z); o.w = f2bf(v.w);
      ((u16x4*)d)[i] = o;
    }
  } else {
    int w = (bid - 3072) * 4 + (t >> 6);  // 64 words
    int lane = t & 63;
    int mk = mask[w * 64 + lane];
    unsigned long long bal = __ballot(mk != 0);
    if (lane == 0) bm[w] = bal;
  }
}

// ---------------- fused QKV projection GEMM (BM=64) ----------------
// grid (24, 64): x<8 -> Q (scaled by 0.125*log2e) row-major; x<16 -> K row-major;
// else V head-transposed out[(b*NE+n)*NS+s]. BM=64, BN=128, BK=64, dbuf.
__global__ __launch_bounds__(256, 3) void gemm_qkv(
    const unsigned short* __restrict__ Aq, const unsigned short* __restrict__ Akv,
    const unsigned short* __restrict__ Wqp, const unsigned short* __restrict__ Wkp,
    const unsigned short* __restrict__ Wvp,
    const float* __restrict__ bqp, const float* __restrict__ bkp, const float* __restrict__ bvp,
    unsigned short* __restrict__ outq, unsigned short* __restrict__ outk,
    unsigned short* __restrict__ outvt) {
  constexpr int BM = 64, K = 1024;
  __shared__ char smem[2 * (BM * 128 + 16384)];
  const int t = threadIdx.x;
  const int lane = t & 63;
  const int wv = t >> 6;
  const int wr = wv >> 1, wc = wv & 1;
  const int x = blockIdx.x;
  const int bm = blockIdx.y * BM;
  const int lr = lane & 15, lg = lane >> 4;

  const unsigned short* A; const unsigned short* Wp; const float* bp;
  unsigned short* outp; int nloc, mode;
  float qsc;
  if (x < 8)       { A = Aq;  Wp = Wqp; bp = bqp; outp = outq;  nloc = x * 128;        mode = 0; qsc = 0.18033688f; }
  else if (x < 16) { A = Akv; Wp = Wkp; bp = bkp; outp = outk;  nloc = (x - 8) * 128;  mode = 0; qsc = 1.0f; }
  else             { A = Akv; Wp = Wvp; bp = bvp; outp = outvt; nloc = (x - 16) * 128; mode = 1; qsc = 1.0f; }

  f32x4 acc[2][4] = {};

  auto stage = [&](int buf, int k0) {
    char* As = smem + buf * (BM * 128 + 16384);
    char* Bs = As + BM * 128;
#pragma unroll
    for (int r = 0; r < 2; ++r) {
      int lin = r * 256 + t;
      int row = lin >> 3;
      int scb = ((lin & 7) << 4) ^ ((row & 7) << 4);
      gload_lds16((const char*)(A + (size_t)(bm + row) * K + k0) + scb,
                  As + (size_t)(r * 256 + (t & ~63)) * 16);
    }
#pragma unroll
    for (int r = 0; r < 4; ++r) {
      int lin = r * 256 + t;
      int row = lin >> 3;
      int scb = ((lin & 7) << 4) ^ ((row & 7) << 4);
      gload_lds16((const char*)(Wp + (size_t)(nloc + row) * K + k0) + scb,
                  Bs + (size_t)(r * 256 + (t & ~63)) * 16);
    }
  };

  stage(0, 0);
  for (int t6 = 0; t6 < K / 64; ++t6) {
    const int cur = t6 & 1;
    if (t6 + 1 < K / 64) {
      stage(cur ^ 1, (t6 + 1) * 64);
      asm volatile("s_waitcnt vmcnt(6)" ::: "memory");
    } else {
      asm volatile("s_waitcnt vmcnt(0)" ::: "memory");
    }
    asm volatile("s_barrier" ::: "memory");

    const char* As = smem + cur * (BM * 128 + 16384);
    const char* Bs = As + BM * 128;
    s16x8 af[2][2], bfr[4][2];
#pragma unroll
    for (int mf = 0; mf < 2; ++mf)
#pragma unroll
      for (int kk = 0; kk < 2; ++kk) {
        int row = wr * 32 + mf * 16 + lr;
        int cb = (lg << 4) + (kk << 6);
        af[mf][kk] = *(const s16x8*)(As + row * 128 + (cb ^ ((row & 7) << 4)));
      }
#pragma unroll
    for (int nf = 0; nf < 4; ++nf)
#pragma unroll
      for (int kk = 0; kk < 2; ++kk) {
        int row = wc * 64 + nf * 16 + lr;
        int cb = (lg << 4) + (kk << 6);
        bfr[nf][kk] = *(const s16x8*)(Bs + row * 128 + (cb ^ ((row & 7) << 4)));
      }
#pragma unroll
    for (int mf = 0; mf < 2; ++mf)
#pragma unroll
      for (int nf = 0; nf < 4; ++nf)
#pragma unroll
        for (int kk = 0; kk < 2; ++kk)
          acc[mf][nf] = mfma16(af[mf][kk], bfr[nf][kk], acc[mf][nf]);

    asm volatile("s_waitcnt lgkmcnt(0)" ::: "memory");
    asm volatile("s_barrier" ::: "memory");
  }

#pragma unroll
  for (int mf = 0; mf < 2; ++mf)
#pragma unroll
    for (int nf = 0; nf < 4; ++nf) {
      int m0 = bm + wr * 32 + mf * 16 + (lg << 2);
      int nc = wc * 64 + nf * 16 + lr;
      float bv = bp[nloc + nc];
      if (mode == 0) {
#pragma unroll
        for (int r = 0; r < 4; ++r)
          outp[(size_t)(m0 + r) * 1024 + nloc + nc] = f2bf((acc[mf][nf][r] + bv) * qsc);
      } else {
        int b = m0 >> 11, s = m0 & 2047;
        u16x4 o;
        o.x = f2bf(acc[mf][nf][0] + bv);
        o.y = f2bf(acc[mf][nf][1] + bv);
        o.z = f2bf(acc[mf][nf][2] + bv);
        o.w = f2bf(acc[mf][nf][3] + bv);
        *(u16x4*)&outp[((size_t)b * NE + nloc + nc) * NS + s] = o;
      }
    }
}

// ---------------- O-projection GEMM (f32 out), BM=64 ----------------
__global__ __launch_bounds__(256, 3) void gemm_o(
    const unsigned short* __restrict__ A, const unsigned short* __restrict__ W,
    const float* __restrict__ bias, float* __restrict__ out) {
  constexpr int BM = 64, K = 1024;
  __shared__ char smem[2 * (BM * 128 + 16384)];
  const int t = threadIdx.x;
  const int lane = t & 63;
  const int wv = t >> 6;
  const int wr = wv >> 1, wc = wv & 1;
  const int bm = blockIdx.y * BM, bn = blockIdx.x * 128;
  const int lr = lane & 15, lg = lane >> 4;

  f32x4 acc[2][4] = {};

  auto stage = [&](int buf, int k0) {
    char* As = smem + buf * (BM * 128 + 16384);
    char* Bs = As + BM * 128;
#pragma unroll
    for (int r = 0; r < 2; ++r) {
      int lin = r * 256 + t;
      int row = lin >> 3;
      int scb = ((lin & 7) << 4) ^ ((row & 7) << 4);
      gload_lds16((const char*)(A + (size_t)(bm + row) * K + k0) + scb,
                  As + (size_t)(r * 256 + (t & ~63)) * 16);
    }
#pragma unroll
    for (int r = 0; r < 4; ++r) {
      int lin = r * 256 + t;
      int row = lin >> 3;
      int scb = ((lin & 7) << 4) ^ ((row & 7) << 4);
      gload_lds16((const char*)(W + (size_t)(bn + row) * K + k0) + scb,
                  Bs + (size_t)(r * 256 + (t & ~63)) * 16);
    }
  };

  stage(0, 0);
  for (int t6 = 0; t6 < K / 64; ++t6) {
    const int cur = t6 & 1;
    if (t6 + 1 < K / 64) {
      stage(cur ^ 1, (t6 + 1) * 64);
      asm volatile("s_waitcnt vmcnt(6)" ::: "memory");
    } else {
      asm volatile("s_waitcnt vmcnt(0)" ::: "memory");
    }
    asm volatile("s_barrier" ::: "memory");

    const char* As = smem + cur * (BM * 128 + 16384);
    const char* Bs = As + BM * 128;
    s16x8 af[2][2], bfr[4][2];
#pragma unroll
    for (int mf = 0; mf < 2; ++mf)
#pragma unroll
      for (int kk = 0; kk < 2; ++kk) {
        int row = wr * 32 + mf * 16 + lr;
        int cb = (lg << 4) + (kk << 6);
        af[mf][kk] = *(const s16x8*)(As + row * 128 + (cb ^ ((row & 7) << 4)));
      }
#pragma unroll
    for (int nf = 0; nf < 4; ++nf)
#pragma unroll
      for (int kk = 0; kk < 2; ++kk) {
        int row = wc * 64 + nf * 16 + lr;
        int cb = (lg << 4) + (kk << 6);
        bfr[nf][kk] = *(const s16x8*)(Bs + row * 128 + (cb ^ ((row & 7) << 4)));
      }
#pragma unroll
    for (int mf = 0; mf < 2; ++mf)
#pragma unroll
      for (int nf = 0; nf < 4; ++nf)
#pragma unroll
        for (int kk = 0; kk < 2; ++kk)
          acc[mf][nf] = mfma16(af[mf][kk], bfr[nf][kk], acc[mf][nf]);

    asm volatile("s_waitcnt lgkmcnt(0)" ::: "memory");
    asm volatile("s_barrier" ::: "memory");
  }

#pragma unroll
  for (int mf = 0; mf < 2; ++mf)
#pragma unroll
    for (int nf = 0; nf < 4; ++nf) {
      int m0 = bm + wr * 32 + mf * 16 + (lg << 2);
      int n = bn + wc * 64 + nf * 16 + lr;
      float bv = bias[n];
#pragma unroll
      for (int r = 0; r < 4; ++r)
        out[(size_t)(m0 + r) * 1024 + n] = acc[mf][nf][r] + bv;
    }
}

// ---------------- Flash attention: key-split x2, 40KB LDS, 3 blocks/CU target ----------------
// grid (S/128, B*H, 2), 256 threads = 4 waves; wave owns 32 q-rows, split sp owns
// keys [sp*1024, sp*1024+1024). Static-max softmax -> partials additive.
// launch_bounds(256,3): caps total VGPR+AGPR at ~170 (natural was 172 -> shave 2,
// no spills expected); 3 x 40KB LDS = 120KB fits -> 3 blocks/CU, 12 waves/CU.
__global__ __launch_bounds__(256, 3) void attn_fwd(
    const unsigned short* __restrict__ qb, const unsigned short* __restrict__ kb,
    const unsigned short* __restrict__ vt, const unsigned long long* __restrict__ bmw,
    unsigned short* __restrict__ op0, unsigned short* __restrict__ op1,
    float* __restrict__ lp) {
  __shared__ char smem[40960];  // K: 2x8KB @0, V: 3x8KB @16384
  const int t = threadIdx.x, lane = t & 63, wv = t >> 6;
  const int l31 = lane & 31, hi = lane >> 5;
  const int sw = (l31 & 15) << 4;
  const int bh = blockIdx.y, b = bh >> 4, h = bh & 15;
  const int sp = blockIdx.z;
  const int kbase = sp * 1024;
  const int q = blockIdx.x * 128 + wv * 32 + l31;
  unsigned short* opp = sp ? op1 : op0;

  // Q fragments (B-operand: col=q=lane&31, k = 16*ks + 8*hi + e); pre-scaled
  s16x8 qf[4];
#pragma unroll
  for (int ks = 0; ks < 4; ++ks)
    qf[ks] = *(const s16x8*)&qb[((size_t)(b * NS + q)) * NE + h * ND + ks * 16 + hi * 8];

  // mask bitmask words: lane i holds word for global tile (i&31)
  unsigned long long mword = bmw[(size_t)b * 32 + l31];
  unsigned mlo = (unsigned)mword, mhi = (unsigned)(mword >> 32);

  // staging source addresses (hoisted); inverse-swizzled global src
  const char* kSrc[2]; const char* vSrc[2]; int ldsO[2];
#pragma unroll
  for (int r = 0; r < 2; ++r) {
    int L = (r * 256 + t) * 16;
    int row = L >> 8;
    int offp = (L & 255) ^ ((row & 15) << 4);
    int rr = row + ((offp >> 7) << 5);
    int byo = offp & 127;
    kSrc[r] = (const char*)&kb[((size_t)(b * NS + kbase) + rr) * NE + h * ND] + byo;
    vSrc[r] = (const char*)&vt[((size_t)((b * NH + h) * ND) + rr) * NS + kbase] + byo;
    ldsO[r] = (r * 256 + (t & ~63)) * 16;
  }

  // frag LDS offsets, shared by K and V tiles ([32 rows][256B], XOR-swizzled)
  int off16[8];
#pragma unroll
  for (int j = 0; j < 8; ++j)
    off16[j] = l31 * 256 + ((j * 32 + hi * 16) ^ sw);

  auto stage = [&](int j) {  // local tile j
    char* kb_ = smem + (j & 1) * 8192;
    char* vb_ = smem + 16384 + (j % 3) * 8192;
#pragma unroll
    for (int r = 0; r < 2; ++r)
      gload_lds16(kSrc[r] + (size_t)j * (64 * NE * 2), kb_ + ldsO[r]);
#pragma unroll
    for (int r = 0; r < 2; ++r)
      gload_lds16(vSrc[r] + (size_t)j * (64 * 2), vb_ + ldsO[r]);
  };

  f32x16 oacc[2] = {};
  f32x8 lacc = {};
  s16x8 pfp[4];  // P fragments of tile t-1

  auto qk = [&](const char* Ks, f32x16& st0, f32x16& st1) {
#pragma unroll
    for (int ks = 0; ks < 4; ++ks) {
      s16x8 kf = *(const s16x8*)(Ks + off16[ks]);
      st0 = mfma32(kf, qf[ks], st0);
    }
#pragma unroll
    for (int ks = 0; ks < 4; ++ks) {
      s16x8 kf = *(const s16x8*)(Ks + off16[4 + ks]);
      st1 = mfma32(kf, qf[ks], st1);
    }
  };

  auto pv = [&](const char* Vs) {
#pragma unroll
    for (int td = 0; td < 2; ++td)
#pragma unroll
      for (int ks = 0; ks < 4; ++ks) {
        s16x8 vf = *(const s16x8*)(Vs + off16[td * 4 + ks]);
        oacc[td] = mfma32(vf, pfp[ks], oacc[td]);
      }
  };

  auto smpack = [&](int tt, f32x16& st0, f32x16& st1) {
#pragma unroll
    for (int r = 0; r < 16; ++r) st0[r] = __builtin_amdgcn_exp2f(st0[r] - 6.0f);
#pragma unroll
    for (int r = 0; r < 16; ++r) st1[r] = __builtin_amdgcn_exp2f(st1[r] - 6.0f);

    int g = sp * NTS + tt;  // global tile index
    unsigned lo = (unsigned)__builtin_amdgcn_readlane((int)mlo, g);
    unsigned hh = (unsigned)__builtin_amdgcn_readlane((int)mhi, g);
    unsigned long long bal = ((unsigned long long)hh << 32) | lo;
    if (bal != ~0ull) {
#pragma unroll
      for (int r = 0; r < 16; ++r) {
        int key0 = (r & 3) + 8 * (r >> 2) + 4 * hi;
        if (!((bal >> key0) & 1)) st0[r] = 0.f;
        if (!((bal >> (key0 + 32)) & 1)) st1[r] = 0.f;
      }
    }

    // 8-reg row-sum accumulator (any partition of the 32 p values works)
#pragma unroll
    for (int r = 0; r < 8; ++r)
      lacc[r] += (st0[r] + st1[r]) + (st0[r + 8] + st1[r + 8]);

#pragma unroll
    for (int ks = 0; ks < 4; ++ks) {
      const int r0 = (ks & 1) * 8;
      unsigned wreg[4];
#pragma unroll
      for (int w = 0; w < 2; ++w) {
        float e0, e1, e2, e3;
        if (ks < 2) {
          e0 = st0[r0 + 2 * w]; e1 = st0[r0 + 2 * w + 1];
          e2 = st0[r0 + 4 + 2 * w]; e3 = st0[r0 + 4 + 2 * w + 1];
        } else {
          e0 = st1[r0 + 2 * w]; e1 = st1[r0 + 2 * w + 1];
          e2 = st1[r0 + 4 + 2 * w]; e3 = st1[r0 + 4 + 2 * w + 1];
        }
        unsigned x = cvtpk_bf16(e0, e1);
        unsigned y = cvtpk_bf16(e2, e3);
        uint2v r2 = __builtin_amdgcn_permlane32_swap(x, y, false, false);
        wreg[w] = r2.x;
        wreg[w + 2] = r2.y;
      }
      union { unsigned u[4]; s16x8 v; } pu;
      pu.u[0] = wreg[0]; pu.u[1] = wreg[1]; pu.u[2] = wreg[2]; pu.u[3] = wreg[3];
      pfp[ks] = pu.v;
    }
  };

  stage(0);
  // peel tile 0
  asm volatile("s_waitcnt vmcnt(0)" ::: "memory");
  __builtin_amdgcn_s_barrier();
  stage(1);
  {
    f32x16 s0 = {}, s1 = {};
    __builtin_amdgcn_s_setprio(1);
    qk(smem, s0, s1);
    __builtin_amdgcn_s_setprio(0);
    smpack(0, s0, s1);
  }

#pragma unroll 1
  for (int tt = 1; tt < NTS; ++tt) {
    asm volatile("s_waitcnt vmcnt(0)" ::: "memory");  // drain stage(tt), issued last iter
    __builtin_amdgcn_s_barrier();
    if (tt + 1 < NTS) stage(tt + 1);

    const char* Kb = smem + (tt & 1) * 8192;
    const char* Vb = smem + 16384 + ((tt - 1) % 3) * 8192;
    f32x16 s0 = {}, s1 = {};
    __builtin_amdgcn_s_setprio(1);
    qk(Kb, s0, s1);   // QK(t)
    pv(Vb);           // PV(t-1)
    __builtin_amdgcn_s_setprio(0);
    smpack(tt, s0, s1);
  }

  // final PV(NTS-1) from vbuf[(NTS-1)%3] = vbuf[0]
  __builtin_amdgcn_s_setprio(1);
  pv(smem + 16384 + ((NTS - 1) % 3) * 8192);
  __builtin_amdgcn_s_setprio(0);

  // l partial (both halves hold same value after cross-half sum)
  float l0 = 0.f;
#pragma unroll
  for (int r = 0; r < 8; ++r) l0 += lacc[r];
  float l = l0 + __shfl_xor(l0, 32);
  if (hi == 0) lp[(((size_t)sp * NB + b) * NH + h) * NS + q] = l;

  // epilogue: UNNORMALIZED O partial; LDS transpose reuses K-pool area -> barrier
  __syncthreads();
  char* Ob = smem + wv * 4096;
#pragma unroll
  for (int td = 0; td < 2; ++td)
#pragma unroll
    for (int i = 0; i < 8; ++i) {
      int r = 2 * i;
      int d = td * 32 + (r & 3) + 8 * (r >> 2) + 4 * hi;
      unsigned pk = cvtpk_bf16(oacc[td][r], oacc[td][r + 1]);
      *(unsigned*)(Ob + l31 * 128 + ((d * 2) ^ ((l31 & 7) << 4))) = pk;
    }
  // wave-local region; no barrier needed
#pragma unroll
  for (int p4 = 0; p4 < 4; ++p4) {
    int lq = p4 * 8 + (lane >> 3);
    int col = (lane & 7) * 16;
    s16x8 v0 = *(const s16x8*)(Ob + lq * 128 + (col ^ ((lq & 7) << 4)));
    int qg = blockIdx.x * 128 + wv * 32 + lq;
    *(s16x8*)((char*)&opp[((size_t)(b * NS + qg)) * NE + h * ND] + col) = v0;
  }
}

// ---------------- combine: ao = (O0 + O1) / (l0 + l1) ----------------
__global__ void attn_combine(const unsigned short* __restrict__ o0,
                             const unsigned short* __restrict__ o1,
                             const float* __restrict__ lp,
                             unsigned short* __restrict__ ao) {
  int idx = blockIdx.x * 256 + threadIdx.x;  // groups of 8 elements
  size_t f = (size_t)idx * 8;
  int b = (int)(f >> 21);
  int s = (int)((f >> 10) & 2047);
  int h = (int)((f >> 6) & 15);
  float l0 = lp[((size_t)(b * NH + h)) * NS + s];
  float l1 = lp[(size_t)NB * NH * NS + ((size_t)(b * NH + h)) * NS + s];
  float inv = 1.0f / (l0 + l1);
  s16x8 a0 = ((const s16x8*)o0)[idx];
  s16x8 a1 = ((const s16x8*)o1)[idx];
  u16x4 r0, r1;
#pragma unroll
  for (int j = 0; j < 4; ++j) {
    float v = (bf2f((unsigned short)a0[j]) + bf2f((unsigned short)a1[j])) * inv;
    ((unsigned short*)&r0)[j] = f2bf(v);
  }
#pragma unroll
  for (int j = 0; j < 4; ++j) {
    float v = (bf2f((unsigned short)a0[4 + j]) + bf2f((unsigned short)a1[4 + j])) * inv;
    ((unsigned short*)&r1)[j] = f2bf(v);
  }
  ((u16x4*)ao)[idx * 2] = r0;
  ((u16x4*)ao)[idx * 2 + 1] = r1;
}

// ---------------- launch ----------------
extern "C" void kernel_launch(void* const* d_in, const int* in_sizes, int n_in,
                              void* d_out, int out_size, void* d_ws, size_t ws_size,
                              hipStream_t stream) {
  const float* queries = (const float*)d_in[0];
  const float* keys = (const float*)d_in[1];
  // d_in[2] (values) is unused by the reference
  const int* mask = (const int*)d_in[3];
  const float* Wq = (const float*)d_in[4];
  const float* bq = (const float*)d_in[5];
  const float* Wk = (const float*)d_in[6];
  const float* bk = (const float*)d_in[7];
  const float* Wv = (const float*)d_in[8];
  const float* bv = (const float*)d_in[9];
  const float* Wo = (const float*)d_in[10];
  const float* bo = (const float*)d_in[11];
  float* out = (float*)d_out;

  char* ws = (char*)d_ws;
  const size_t SZ_X = (size_t)NB * NS * NE * 2;  // 8 MiB
  const size_t SZ_W = (size_t)NE * NE * 2;       // 2 MiB
  unsigned short* qbf = (unsigned short*)(ws);
  unsigned short* kbf = (unsigned short*)(ws + SZ_X);
  unsigned short* wqb = (unsigned short*)(ws + 2 * SZ_X);
  unsigned short* wkb = (unsigned short*)(ws + 2 * SZ_X + SZ_W);
  unsigned short* wvb = (unsigned short*)(ws + 2 * SZ_X + 2 * SZ_W);
  unsigned short* wob = (unsigned short*)(ws + 2 * SZ_X + 3 * SZ_W);
  unsigned short* qp  = (unsigned short*)(ws + 2 * SZ_X + 4 * SZ_W);
  unsigned short* kp  = (unsigned short*)(ws + 3 * SZ_X + 4 * SZ_W);
  unsigned short* vtp = (unsigned short*)(ws + 4 * SZ_X + 4 * SZ_W);
  unsigned short* ao  = (unsigned short*)(ws + 5 * SZ_X + 4 * SZ_W);
  unsigned long long* bmp = (unsigned long long*)(ws + 6 * SZ_X + 4 * SZ_W);
  // partial buffers alias dead regions (qbf/kbf consumed by gemm_qkv):
  unsigned short* op0 = qbf;              // 8 MiB
  unsigned short* op1 = kbf;              // 8 MiB
  float* lpart = (float*)wqb;             // 512 KiB (within 2 MiB region)

  // fused prologue: converts + mask pack (1 launch)
  prep<<<3088, 256, 0, stream>>>(queries, keys, qbf, kbf,
                                 Wq, Wk, Wv, Wo, wqb, wkb, wvb, wob,
                                 mask, bmp);

  // fused Q + K + V projections (BM=64; Q pre-scaled by 0.125*log2e)
  gemm_qkv<<<dim3(24, 64), 256, 0, stream>>>(qbf, kbf, wqb, wkb, wvb,
                                             bq, bk, bv, qp, kp, vtp);

  dim3 ga(NS / 128, NB * NH, 2);  // (16, 32, 2) = 1024 blocks
  attn_fwd<<<ga, 256, 0, stream>>>(qp, kp, vtp, bmp, op0, op1, lpart);
  attn_combine<<<4096, 256, 0, stream>>>(op0, op1, lpart, ao);

  // output projection: f32 out
  gemm_o<<<dim3(8, 64), 256, 0, stream>>>(ao, wob, bo, out);
}

// Round 11
// 110.726 us; speedup vs baseline: 1.1192x; 1.1192x over previous
//
#include <hip/hip_runtime.h>
#include <hip/hip_bf16.h>
#include <stdint.h>

// Problem constants
#define NB 2
#define NS 2048
#define NE 1024
#define NH 16
#define ND 64
#define NT 32  // K-tiles (NS/64)

typedef __attribute__((ext_vector_type(4))) float f32x4;
typedef __attribute__((ext_vector_type(16))) float f32x16;
typedef __attribute__((ext_vector_type(8))) short s16x8;
typedef __attribute__((ext_vector_type(4))) unsigned short u16x4;
typedef __attribute__((ext_vector_type(2))) unsigned int uint2v;

__device__ __forceinline__ unsigned short f2bf(float f) {
  union { float f; unsigned int i; } u; u.f = f;
  unsigned int r = u.i + 0x7FFFu + ((u.i >> 16) & 1u);  // RNE
  return (unsigned short)(r >> 16);
}

__device__ __forceinline__ unsigned cvtpk_bf16(float lo, float hi) {
  unsigned r;
  asm("v_cvt_pk_bf16_f32 %0, %1, %2" : "=v"(r) : "v"(lo), "v"(hi));
  return r;
}

__device__ __forceinline__ void gload_lds16(const void* g, void* l) {
  __builtin_amdgcn_global_load_lds(
      (const __attribute__((address_space(1))) uint32_t*)g,
      (__attribute__((address_space(3))) uint32_t*)l, 16, 0, 0);
}

__device__ __forceinline__ f32x4 mfma16(s16x8 a, s16x8 b, f32x4 c) {
  return __builtin_amdgcn_mfma_f32_16x16x32_bf16(a, b, c, 0, 0, 0);
}
__device__ __forceinline__ f32x16 mfma32(s16x8 a, s16x8 b, f32x16 c) {
  return __builtin_amdgcn_mfma_f32_32x32x16_bf16(a, b, c, 0, 0, 0);
}

// ---------------- fused prologue: f32->bf16 converts + mask pack (1 launch) ----------------
// grid 3088 x 256: [0,2048) X-converts (q,k); [2048,3072) W-converts; [3072,3088) mask.
__global__ void prep(const float* __restrict__ xq, const float* __restrict__ xk,
                     unsigned short* __restrict__ dq, unsigned short* __restrict__ dk,
                     const float* __restrict__ w0, const float* __restrict__ w1,
                     const float* __restrict__ w2, const float* __restrict__ w3,
                     unsigned short* __restrict__ e0, unsigned short* __restrict__ e1,
                     unsigned short* __restrict__ e2, unsigned short* __restrict__ e3,
                     const int* __restrict__ mask, unsigned long long* __restrict__ bm) {
  const int bid = blockIdx.x, t = threadIdx.x;
  if (bid < 2048) {
    const float* s = (bid < 1024) ? xq : xk;
    unsigned short* d = (bid < 1024) ? dq : dk;
    int i = (bid & 1023) * 256 + t;
    const int n4 = NB * NS * NE / 4, stride = 1024 * 256;
    for (; i < n4; i += stride) {
      float4 v = ((const float4*)s)[i];
      u16x4 o;
      o.x = f2bf(v.x); o.y = f2bf(v.y); o.z = f2bf(v.z); o.w = f2bf(v.w);
      ((u16x4*)d)[i] = o;
    }
  } else if (bid < 3072) {
    int seg = (bid - 2048) >> 8;
    const float* s; unsigned short* d;
    switch (seg) {
      case 0: s = w0; d = e0; break;
      case 1: s = w1; d = e1; break;
      case 2: s = w2; d = e2; break;
      default: s = w3; d = e3; break;
    }
    int i = ((bid - 2048) & 255) * 256 + t;
    const int n4 = NE * NE / 4, stride = 256 * 256;
    for (; i < n4; i += stride) {
      float4 v = ((const float4*)s)[i];
      u16x4 o;
      o.x = f2bf(v.x); o.y = f2bf(v.y); o.z = f2bf(v.z); o.w = f2bf(v.w);
      ((u16x4*)d)[i] = o;
    }
  } else {
    int w = (bid - 3072) * 4 + (t >> 6);  // 64 words
    int lane = t & 63;
    int mk = mask[w * 64 + lane];
    unsigned long long bal = __ballot(mk != 0);
    if (lane == 0) bm[w] = bal;
  }
}

// ---------------- fused QKV projection GEMM (BM=64) ----------------
// grid (24, 64): x<8 -> Q (scaled by 0.125*log2e) row-major; x<16 -> K row-major;
// else V head-transposed out[(b*NE+n)*NS+s]. BM=64, BN=128, BK=64, dbuf.
__global__ __launch_bounds__(256, 3) void gemm_qkv(
    const unsigned short* __restrict__ Aq, const unsigned short* __restrict__ Akv,
    const unsigned short* __restrict__ Wqp, const unsigned short* __restrict__ Wkp,
    const unsigned short* __restrict__ Wvp,
    const float* __restrict__ bqp, const float* __restrict__ bkp, const float* __restrict__ bvp,
    unsigned short* __restrict__ outq, unsigned short* __restrict__ outk,
    unsigned short* __restrict__ outvt) {
  constexpr int BM = 64, K = 1024;
  __shared__ char smem[2 * (BM * 128 + 16384)];
  const int t = threadIdx.x;
  const int lane = t & 63;
  const int wv = t >> 6;
  const int wr = wv >> 1, wc = wv & 1;
  const int x = blockIdx.x;
  const int bm = blockIdx.y * BM;
  const int lr = lane & 15, lg = lane >> 4;

  const unsigned short* A; const unsigned short* Wp; const float* bp;
  unsigned short* outp; int nloc, mode;
  float qsc;
  if (x < 8)       { A = Aq;  Wp = Wqp; bp = bqp; outp = outq;  nloc = x * 128;        mode = 0; qsc = 0.18033688f; }
  else if (x < 16) { A = Akv; Wp = Wkp; bp = bkp; outp = outk;  nloc = (x - 8) * 128;  mode = 0; qsc = 1.0f; }
  else             { A = Akv; Wp = Wvp; bp = bvp; outp = outvt; nloc = (x - 16) * 128; mode = 1; qsc = 1.0f; }

  f32x4 acc[2][4] = {};

  auto stage = [&](int buf, int k0) {
    char* As = smem + buf * (BM * 128 + 16384);
    char* Bs = As + BM * 128;
#pragma unroll
    for (int r = 0; r < 2; ++r) {
      int lin = r * 256 + t;
      int row = lin >> 3;
      int scb = ((lin & 7) << 4) ^ ((row & 7) << 4);
      gload_lds16((const char*)(A + (size_t)(bm + row) * K + k0) + scb,
                  As + (size_t)(r * 256 + (t & ~63)) * 16);
    }
#pragma unroll
    for (int r = 0; r < 4; ++r) {
      int lin = r * 256 + t;
      int row = lin >> 3;
      int scb = ((lin & 7) << 4) ^ ((row & 7) << 4);
      gload_lds16((const char*)(Wp + (size_t)(nloc + row) * K + k0) + scb,
                  Bs + (size_t)(r * 256 + (t & ~63)) * 16);
    }
  };

  stage(0, 0);
  for (int t6 = 0; t6 < K / 64; ++t6) {
    const int cur = t6 & 1;
    if (t6 + 1 < K / 64) {
      stage(cur ^ 1, (t6 + 1) * 64);
      asm volatile("s_waitcnt vmcnt(6)" ::: "memory");
    } else {
      asm volatile("s_waitcnt vmcnt(0)" ::: "memory");
    }
    asm volatile("s_barrier" ::: "memory");

    const char* As = smem + cur * (BM * 128 + 16384);
    const char* Bs = As + BM * 128;
    s16x8 af[2][2], bfr[4][2];
#pragma unroll
    for (int mf = 0; mf < 2; ++mf)
#pragma unroll
      for (int kk = 0; kk < 2; ++kk) {
        int row = wr * 32 + mf * 16 + lr;
        int cb = (lg << 4) + (kk << 6);
        af[mf][kk] = *(const s16x8*)(As + row * 128 + (cb ^ ((row & 7) << 4)));
      }
#pragma unroll
    for (int nf = 0; nf < 4; ++nf)
#pragma unroll
      for (int kk = 0; kk < 2; ++kk) {
        int row = wc * 64 + nf * 16 + lr;
        int cb = (lg << 4) + (kk << 6);
        bfr[nf][kk] = *(const s16x8*)(Bs + row * 128 + (cb ^ ((row & 7) << 4)));
      }
#pragma unroll
    for (int mf = 0; mf < 2; ++mf)
#pragma unroll
      for (int nf = 0; nf < 4; ++nf)
#pragma unroll
        for (int kk = 0; kk < 2; ++kk)
          acc[mf][nf] = mfma16(af[mf][kk], bfr[nf][kk], acc[mf][nf]);

    asm volatile("s_waitcnt lgkmcnt(0)" ::: "memory");
    asm volatile("s_barrier" ::: "memory");
  }

#pragma unroll
  for (int mf = 0; mf < 2; ++mf)
#pragma unroll
    for (int nf = 0; nf < 4; ++nf) {
      int m0 = bm + wr * 32 + mf * 16 + (lg << 2);
      int nc = wc * 64 + nf * 16 + lr;
      float bv = bp[nloc + nc];
      if (mode == 0) {
#pragma unroll
        for (int r = 0; r < 4; ++r)
          outp[(size_t)(m0 + r) * 1024 + nloc + nc] = f2bf((acc[mf][nf][r] + bv) * qsc);
      } else {
        int b = m0 >> 11, s = m0 & 2047;
        u16x4 o;
        o.x = f2bf(acc[mf][nf][0] + bv);
        o.y = f2bf(acc[mf][nf][1] + bv);
        o.z = f2bf(acc[mf][nf][2] + bv);
        o.w = f2bf(acc[mf][nf][3] + bv);
        *(u16x4*)&outp[((size_t)b * NE + nloc + nc) * NS + s] = o;
      }
    }
}

// ---------------- O-projection GEMM (f32 out), BM=64 ----------------
__global__ __launch_bounds__(256, 3) void gemm_o(
    const unsigned short* __restrict__ A, const unsigned short* __restrict__ W,
    const float* __restrict__ bias, float* __restrict__ out) {
  constexpr int BM = 64, K = 1024;
  __shared__ char smem[2 * (BM * 128 + 16384)];
  const int t = threadIdx.x;
  const int lane = t & 63;
  const int wv = t >> 6;
  const int wr = wv >> 1, wc = wv & 1;
  const int bm = blockIdx.y * BM, bn = blockIdx.x * 128;
  const int lr = lane & 15, lg = lane >> 4;

  f32x4 acc[2][4] = {};

  auto stage = [&](int buf, int k0) {
    char* As = smem + buf * (BM * 128 + 16384);
    char* Bs = As + BM * 128;
#pragma unroll
    for (int r = 0; r < 2; ++r) {
      int lin = r * 256 + t;
      int row = lin >> 3;
      int scb = ((lin & 7) << 4) ^ ((row & 7) << 4);
      gload_lds16((const char*)(A + (size_t)(bm + row) * K + k0) + scb,
                  As + (size_t)(r * 256 + (t & ~63)) * 16);
    }
#pragma unroll
    for (int r = 0; r < 4; ++r) {
      int lin = r * 256 + t;
      int row = lin >> 3;
      int scb = ((lin & 7) << 4) ^ ((row & 7) << 4);
      gload_lds16((const char*)(W + (size_t)(bn + row) * K + k0) + scb,
                  Bs + (size_t)(r * 256 + (t & ~63)) * 16);
    }
  };

  stage(0, 0);
  for (int t6 = 0; t6 < K / 64; ++t6) {
    const int cur = t6 & 1;
    if (t6 + 1 < K / 64) {
      stage(cur ^ 1, (t6 + 1) * 64);
      asm volatile("s_waitcnt vmcnt(6)" ::: "memory");
    } else {
      asm volatile("s_waitcnt vmcnt(0)" ::: "memory");
    }
    asm volatile("s_barrier" ::: "memory");

    const char* As = smem + cur * (BM * 128 + 16384);
    const char* Bs = As + BM * 128;
    s16x8 af[2][2], bfr[4][2];
#pragma unroll
    for (int mf = 0; mf < 2; ++mf)
#pragma unroll
      for (int kk = 0; kk < 2; ++kk) {
        int row = wr * 32 + mf * 16 + lr;
        int cb = (lg << 4) + (kk << 6);
        af[mf][kk] = *(const s16x8*)(As + row * 128 + (cb ^ ((row & 7) << 4)));
      }
#pragma unroll
    for (int nf = 0; nf < 4; ++nf)
#pragma unroll
      for (int kk = 0; kk < 2; ++kk) {
        int row = wc * 64 + nf * 16 + lr;
        int cb = (lg << 4) + (kk << 6);
        bfr[nf][kk] = *(const s16x8*)(Bs + row * 128 + (cb ^ ((row & 7) << 4)));
      }
#pragma unroll
    for (int mf = 0; mf < 2; ++mf)
#pragma unroll
      for (int nf = 0; nf < 4; ++nf)
#pragma unroll
        for (int kk = 0; kk < 2; ++kk)
          acc[mf][nf] = mfma16(af[mf][kk], bfr[nf][kk], acc[mf][nf]);

    asm volatile("s_waitcnt lgkmcnt(0)" ::: "memory");
    asm volatile("s_barrier" ::: "memory");
  }

#pragma unroll
  for (int mf = 0; mf < 2; ++mf)
#pragma unroll
    for (int nf = 0; nf < 4; ++nf) {
      int m0 = bm + wr * 32 + mf * 16 + (lg << 2);
      int n = bn + wc * 64 + nf * 16 + lr;
      float bv = bias[n];
#pragma unroll
      for (int r = 0; r < 4; ++r)
        out[(size_t)(m0 + r) * 1024 + n] = acc[mf][nf][r] + bv;
    }
}

// ---------------- Flash attention: T15 cross-tile pipeline (round-7 best) ----------------
// grid (S/128, B*H), 256 threads = 4 waves; wave owns 32 q-rows.
// Static-max softmax (Q pre-scaled by 0.125*log2e; p = exp2(st-6), exact after norm).
// Per-iter: vmcnt(4) -> barrier -> stage(t+2) -> [QK(t) + PV(t-1)] MFMA cluster
// -> softmax+pack(t). 4 LDS buffers; V(t-1) survives via mod-4 rotation.
__global__ __launch_bounds__(256, 2) void attn_fwd(
    const unsigned short* __restrict__ qb, const unsigned short* __restrict__ kb,
    const unsigned short* __restrict__ vt, const unsigned long long* __restrict__ bmw,
    unsigned short* __restrict__ ob) {
  __shared__ char smem[65536];  // 4 bufs x (K 8KB | V 8KB)
  const int t = threadIdx.x, lane = t & 63, wv = t >> 6;
  const int l31 = lane & 31, hi = lane >> 5;
  const int sw = (l31 & 15) << 4;
  const int bh = blockIdx.y, b = bh >> 4, h = bh & 15;
  const int q = blockIdx.x * 128 + wv * 32 + l31;

  // Q fragments (B-operand: col=q=lane&31, k = 16*ks + 8*hi + e); pre-scaled
  s16x8 qf[4];
#pragma unroll
  for (int ks = 0; ks < 4; ++ks)
    qf[ks] = *(const s16x8*)&qb[((size_t)(b * NS + q)) * NE + h * ND + ks * 16 + hi * 8];

  // mask bitmask words: lane i holds word for tile (i&31)
  unsigned long long mword = bmw[(size_t)b * 32 + l31];
  unsigned mlo = (unsigned)mword, mhi = (unsigned)(mword >> 32);

  // staging source addresses (hoisted); inverse-swizzled global src
  const char* kSrc[2]; const char* vSrc[2]; int ldsK[2], ldsV[2];
#pragma unroll
  for (int r = 0; r < 2; ++r) {
    int L = (r * 256 + t) * 16;
    int row = L >> 8;
    int offp = (L & 255) ^ ((row & 15) << 4);
    int rr = row + ((offp >> 7) << 5);
    int byo = offp & 127;
    kSrc[r] = (const char*)&kb[((size_t)(b * NS) + rr) * NE + h * ND] + byo;
    vSrc[r] = (const char*)&vt[((size_t)((b * NH + h) * ND) + rr) * NS] + byo;
    ldsK[r] = (r * 256 + (t & ~63)) * 16;
    ldsV[r] = 8192 + ldsK[r];
  }

  // frag LDS offsets, shared by K and V
  int off16[8];
#pragma unroll
  for (int j = 0; j < 8; ++j)
    off16[j] = l31 * 256 + ((j * 32 + hi * 16) ^ sw);

  auto stage = [&](int buf, int kt) {
    char* base = smem + buf * 16384;
#pragma unroll
    for (int r = 0; r < 2; ++r)
      gload_lds16(kSrc[r] + (size_t)kt * (NE * 2), base + ldsK[r]);
#pragma unroll
    for (int r = 0; r < 2; ++r)
      gload_lds16(vSrc[r] + (size_t)kt * 2, base + ldsV[r]);
  };

  f32x16 oacc[2] = {};
  f32x16 lacc = {};
  s16x8 pfp[4];  // P fragments of tile t-1, carried across iterations

  auto qk = [&](const char* Ks, f32x16& st0, f32x16& st1) {
#pragma unroll
    for (int ks = 0; ks < 4; ++ks) {
      s16x8 kf = *(const s16x8*)(Ks + off16[ks]);
      st0 = mfma32(kf, qf[ks], st0);
    }
#pragma unroll
    for (int ks = 0; ks < 4; ++ks) {
      s16x8 kf = *(const s16x8*)(Ks + off16[4 + ks]);
      st1 = mfma32(kf, qf[ks], st1);
    }
  };

  auto pv = [&](const char* Vs) {
#pragma unroll
    for (int td = 0; td < 2; ++td)
#pragma unroll
      for (int ks = 0; ks < 4; ++ks) {
        s16x8 vf = *(const s16x8*)(Vs + off16[td * 4 + ks]);
        oacc[td] = mfma32(vf, pfp[ks], oacc[td]);
      }
  };

  auto smpack = [&](int tt, f32x16& st0, f32x16& st1) {
    // static-max exp: p = exp2(st - 6)
#pragma unroll
    for (int r = 0; r < 16; ++r) st0[r] = __builtin_amdgcn_exp2f(st0[r] - 6.0f);
#pragma unroll
    for (int r = 0; r < 16; ++r) st1[r] = __builtin_amdgcn_exp2f(st1[r] - 6.0f);

    // mask via prepacked bitmask (fast path: all-ones)
    unsigned lo = (unsigned)__builtin_amdgcn_readlane((int)mlo, tt);
    unsigned hh = (unsigned)__builtin_amdgcn_readlane((int)mhi, tt);
    unsigned long long bal = ((unsigned long long)hh << 32) | lo;
    if (bal != ~0ull) {
#pragma unroll
      for (int r = 0; r < 16; ++r) {
        int key0 = (r & 3) + 8 * (r >> 2) + 4 * hi;
        if (!((bal >> key0) & 1)) st0[r] = 0.f;
        if (!((bal >> (key0 + 32)) & 1)) st1[r] = 0.f;
      }
    }

    lacc += st0;
    lacc += st1;

    // pack P -> PV B-fragments (T12: cvt_pk + permlane32_swap)
#pragma unroll
    for (int ks = 0; ks < 4; ++ks) {
      const int r0 = (ks & 1) * 8;
      unsigned wreg[4];
#pragma unroll
      for (int w = 0; w < 2; ++w) {
        float e0, e1, e2, e3;
        if (ks < 2) {
          e0 = st0[r0 + 2 * w]; e1 = st0[r0 + 2 * w + 1];
          e2 = st0[r0 + 4 + 2 * w]; e3 = st0[r0 + 4 + 2 * w + 1];
        } else {
          e0 = st1[r0 + 2 * w]; e1 = st1[r0 + 2 * w + 1];
          e2 = st1[r0 + 4 + 2 * w]; e3 = st1[r0 + 4 + 2 * w + 1];
        }
        unsigned x = cvtpk_bf16(e0, e1);
        unsigned y = cvtpk_bf16(e2, e3);
        uint2v r2 = __builtin_amdgcn_permlane32_swap(x, y, false, false);
        wreg[w] = r2.x;
        wreg[w + 2] = r2.y;
      }
      union { unsigned u[4]; s16x8 v; } pu;
      pu.u[0] = wreg[0]; pu.u[1] = wreg[1]; pu.u[2] = wreg[2]; pu.u[3] = wreg[3];
      pfp[ks] = pu.v;
    }
  };

  stage(0, 0);
  stage(1, 64);

  // peel tile 0: QK + softmax only
  asm volatile("s_waitcnt vmcnt(4)" ::: "memory");
  __builtin_amdgcn_s_barrier();
  stage(2, 128);
  {
    f32x16 s0 = {}, s1 = {};
    __builtin_amdgcn_s_setprio(1);
    qk(smem, s0, s1);
    __builtin_amdgcn_s_setprio(0);
    smpack(0, s0, s1);
  }

#pragma unroll 1
  for (int tt = 1; tt < NT; ++tt) {
    if (tt + 1 < NT) {
      asm volatile("s_waitcnt vmcnt(4)" ::: "memory");
    } else {
      asm volatile("s_waitcnt vmcnt(0)" ::: "memory");
    }
    __builtin_amdgcn_s_barrier();
    if (tt + 2 < NT) stage((tt + 2) & 3, (tt + 2) * 64);

    const char* Kb = smem + (tt & 3) * 16384;
    const char* Vb = smem + ((tt - 1) & 3) * 16384 + 8192;
    f32x16 s0 = {}, s1 = {};
    __builtin_amdgcn_s_setprio(1);
    qk(Kb, s0, s1);   // QK(t)
    pv(Vb);           // PV(t-1) — same MFMA cluster
    __builtin_amdgcn_s_setprio(0);
    smpack(tt, s0, s1);
  }

  // final PV(NT-1); its V buffer is untouched after the last stage
  __builtin_amdgcn_s_setprio(1);
  pv(smem + ((NT - 1) & 3) * 16384 + 8192);
  __builtin_amdgcn_s_setprio(0);

  // epilogue: l = tree(lacc) + cross-half; normalize, LDS transpose, store
  float l0 = 0.f;
#pragma unroll
  for (int r = 0; r < 16; ++r) l0 += lacc[r];
  float l = l0 + __shfl_xor(l0, 32);
  float inv = 1.0f / l;

  char* Ob = smem + wv * 4096;
#pragma unroll
  for (int td = 0; td < 2; ++td)
#pragma unroll
    for (int i = 0; i < 8; ++i) {
      int r = 2 * i;
      int d = td * 32 + (r & 3) + 8 * (r >> 2) + 4 * hi;
      unsigned pk = cvtpk_bf16(oacc[td][r] * inv, oacc[td][r + 1] * inv);
      *(unsigned*)(Ob + l31 * 128 + ((d * 2) ^ ((l31 & 7) << 4))) = pk;
    }
  // wave-local region (buf0/1 K areas; final PV reads buf3 V area) — no barrier
#pragma unroll
  for (int p4 = 0; p4 < 4; ++p4) {
    int lq = p4 * 8 + (lane >> 3);
    int col = (lane & 7) * 16;
    s16x8 v0 = *(const s16x8*)(Ob + lq * 128 + (col ^ ((lq & 7) << 4)));
    int qg = blockIdx.x * 128 + wv * 32 + lq;
    *(s16x8*)((char*)&ob[((size_t)(b * NS + qg)) * NE + h * ND] + col) = v0;
  }
}

// ---------------- launch ----------------
extern "C" void kernel_launch(void* const* d_in, const int* in_sizes, int n_in,
                              void* d_out, int out_size, void* d_ws, size_t ws_size,
                              hipStream_t stream) {
  const float* queries = (const float*)d_in[0];
  const float* keys = (const float*)d_in[1];
  // d_in[2] (values) is unused by the reference
  const int* mask = (const int*)d_in[3];
  const float* Wq = (const float*)d_in[4];
  const float* bq = (const float*)d_in[5];
  const float* Wk = (const float*)d_in[6];
  const float* bk = (const float*)d_in[7];
  const float* Wv = (const float*)d_in[8];
  const float* bv = (const float*)d_in[9];
  const float* Wo = (const float*)d_in[10];
  const float* bo = (const float*)d_in[11];
  float* out = (float*)d_out;

  char* ws = (char*)d_ws;
  const size_t SZ_X = (size_t)NB * NS * NE * 2;  // 8 MiB
  const size_t SZ_W = (size_t)NE * NE * 2;       // 2 MiB
  unsigned short* qbf = (unsigned short*)(ws);
  unsigned short* kbf = (unsigned short*)(ws + SZ_X);
  unsigned short* wqb = (unsigned short*)(ws + 2 * SZ_X);
  unsigned short* wkb = (unsigned short*)(ws + 2 * SZ_X + SZ_W);
  unsigned short* wvb = (unsigned short*)(ws + 2 * SZ_X + 2 * SZ_W);
  unsigned short* wob = (unsigned short*)(ws + 2 * SZ_X + 3 * SZ_W);
  unsigned short* qp  = (unsigned short*)(ws + 2 * SZ_X + 4 * SZ_W);
  unsigned short* kp  = (unsigned short*)(ws + 3 * SZ_X + 4 * SZ_W);
  unsigned short* vtp = (unsigned short*)(ws + 4 * SZ_X + 4 * SZ_W);
  unsigned short* ao  = (unsigned short*)(ws + 5 * SZ_X + 4 * SZ_W);
  unsigned long long* bmp = (unsigned long long*)(ws + 6 * SZ_X + 4 * SZ_W);

  // fused prologue: converts + mask pack (1 launch)
  prep<<<3088, 256, 0, stream>>>(queries, keys, qbf, kbf,
                                 Wq, Wk, Wv, Wo, wqb, wkb, wvb, wob,
                                 mask, bmp);

  // fused Q + K + V projections (BM=64; Q pre-scaled by 0.125*log2e)
  gemm_qkv<<<dim3(24, 64), 256, 0, stream>>>(qbf, kbf, wqb, wkb, wvb,
                                             bq, bk, bv, qp, kp, vtp);

  dim3 ga(NS / 128, NB * NH);  // (16, 32)
  attn_fwd<<<ga, 256, 0, stream>>>(qp, kp, vtp, bmp, ao);

  // output projection: f32 out
  gemm_o<<<dim3(8, 64), 256, 0, stream>>>(ao, wob, bo, out);
}

// Round 12
// 108.501 us; speedup vs baseline: 1.1422x; 1.0205x over previous
//
#include <hip/hip_runtime.h>
#include <hip/hip_bf16.h>
#include <stdint.h>

// Problem constants
#define NB 2
#define NS 2048
#define NE 1024
#define NH 16
#define ND 64
#define NT 32  // K-tiles (NS/64)

typedef __attribute__((ext_vector_type(4))) float f32x4;
typedef __attribute__((ext_vector_type(16))) float f32x16;
typedef __attribute__((ext_vector_type(8))) short s16x8;
typedef __attribute__((ext_vector_type(4))) unsigned short u16x4;
typedef __attribute__((ext_vector_type(2))) unsigned int uint2v;

__device__ __forceinline__ unsigned short f2bf(float f) {
  union { float f; unsigned int i; } u; u.f = f;
  unsigned int r = u.i + 0x7FFFu + ((u.i >> 16) & 1u);  // RNE
  return (unsigned short)(r >> 16);
}

__device__ __forceinline__ unsigned cvtpk_bf16(float lo, float hi) {
  unsigned r;
  asm("v_cvt_pk_bf16_f32 %0, %1, %2" : "=v"(r) : "v"(lo), "v"(hi));
  return r;
}

__device__ __forceinline__ void gload_lds16(const void* g, void* l) {
  __builtin_amdgcn_global_load_lds(
      (const __attribute__((address_space(1))) uint32_t*)g,
      (__attribute__((address_space(3))) uint32_t*)l, 16, 0, 0);
}

__device__ __forceinline__ f32x4 mfma16(s16x8 a, s16x8 b, f32x4 c) {
  return __builtin_amdgcn_mfma_f32_16x16x32_bf16(a, b, c, 0, 0, 0);
}
__device__ __forceinline__ f32x16 mfma32(s16x8 a, s16x8 b, f32x16 c) {
  return __builtin_amdgcn_mfma_f32_32x32x16_bf16(a, b, c, 0, 0, 0);
}

// ---------------- fused prologue: f32->bf16 converts + mask pack (1 launch) ----------------
// grid 3088 x 256: [0,2048) X-converts (q,k); [2048,3072) W-converts; [3072,3088) mask.
__global__ void prep(const float* __restrict__ xq, const float* __restrict__ xk,
                     unsigned short* __restrict__ dq, unsigned short* __restrict__ dk,
                     const float* __restrict__ w0, const float* __restrict__ w1,
                     const float* __restrict__ w2, const float* __restrict__ w3,
                     unsigned short* __restrict__ e0, unsigned short* __restrict__ e1,
                     unsigned short* __restrict__ e2, unsigned short* __restrict__ e3,
                     const int* __restrict__ mask, unsigned long long* __restrict__ bm) {
  const int bid = blockIdx.x, t = threadIdx.x;
  if (bid < 2048) {
    const float* s = (bid < 1024) ? xq : xk;
    unsigned short* d = (bid < 1024) ? dq : dk;
    int i = (bid & 1023) * 256 + t;
    const int n4 = NB * NS * NE / 4, stride = 1024 * 256;
    for (; i < n4; i += stride) {
      float4 v = ((const float4*)s)[i];
      u16x4 o;
      o.x = f2bf(v.x); o.y = f2bf(v.y); o.z = f2bf(v.z); o.w = f2bf(v.w);
      ((u16x4*)d)[i] = o;
    }
  } else if (bid < 3072) {
    int seg = (bid - 2048) >> 8;
    const float* s; unsigned short* d;
    switch (seg) {
      case 0: s = w0; d = e0; break;
      case 1: s = w1; d = e1; break;
      case 2: s = w2; d = e2; break;
      default: s = w3; d = e3; break;
    }
    int i = ((bid - 2048) & 255) * 256 + t;
    const int n4 = NE * NE / 4, stride = 256 * 256;
    for (; i < n4; i += stride) {
      float4 v = ((const float4*)s)[i];
      u16x4 o;
      o.x = f2bf(v.x); o.y = f2bf(v.y); o.z = f2bf(v.z); o.w = f2bf(v.w);
      ((u16x4*)d)[i] = o;
    }
  } else {
    int w = (bid - 3072) * 4 + (t >> 6);  // 64 words
    int lane = t & 63;
    int mk = mask[w * 64 + lane];
    unsigned long long bal = __ballot(mk != 0);
    if (lane == 0) bm[w] = bal;
  }
}

// ---------------- fused QKV projection GEMM (BM=64) ----------------
// grid (24, 64): x<8 -> Q (scaled by 0.125*log2e) row-major; x<16 -> K row-major;
// else V head-transposed out[(b*NE+n)*NS+s]. BM=64, BN=128, BK=64, dbuf.
__global__ __launch_bounds__(256, 3) void gemm_qkv(
    const unsigned short* __restrict__ Aq, const unsigned short* __restrict__ Akv,
    const unsigned short* __restrict__ Wqp, const unsigned short* __restrict__ Wkp,
    const unsigned short* __restrict__ Wvp,
    const float* __restrict__ bqp, const float* __restrict__ bkp, const float* __restrict__ bvp,
    unsigned short* __restrict__ outq, unsigned short* __restrict__ outk,
    unsigned short* __restrict__ outvt) {
  constexpr int BM = 64, K = 1024;
  __shared__ char smem[2 * (BM * 128 + 16384)];
  const int t = threadIdx.x;
  const int lane = t & 63;
  const int wv = t >> 6;
  const int wr = wv >> 1, wc = wv & 1;
  const int x = blockIdx.x;
  const int bm = blockIdx.y * BM;
  const int lr = lane & 15, lg = lane >> 4;

  const unsigned short* A; const unsigned short* Wp; const float* bp;
  unsigned short* outp; int nloc, mode;
  float qsc;
  if (x < 8)       { A = Aq;  Wp = Wqp; bp = bqp; outp = outq;  nloc = x * 128;        mode = 0; qsc = 0.18033688f; }
  else if (x < 16) { A = Akv; Wp = Wkp; bp = bkp; outp = outk;  nloc = (x - 8) * 128;  mode = 0; qsc = 1.0f; }
  else             { A = Akv; Wp = Wvp; bp = bvp; outp = outvt; nloc = (x - 16) * 128; mode = 1; qsc = 1.0f; }

  f32x4 acc[2][4] = {};

  auto stage = [&](int buf, int k0) {
    char* As = smem + buf * (BM * 128 + 16384);
    char* Bs = As + BM * 128;
#pragma unroll
    for (int r = 0; r < 2; ++r) {
      int lin = r * 256 + t;
      int row = lin >> 3;
      int scb = ((lin & 7) << 4) ^ ((row & 7) << 4);
      gload_lds16((const char*)(A + (size_t)(bm + row) * K + k0) + scb,
                  As + (size_t)(r * 256 + (t & ~63)) * 16);
    }
#pragma unroll
    for (int r = 0; r < 4; ++r) {
      int lin = r * 256 + t;
      int row = lin >> 3;
      int scb = ((lin & 7) << 4) ^ ((row & 7) << 4);
      gload_lds16((const char*)(Wp + (size_t)(nloc + row) * K + k0) + scb,
                  Bs + (size_t)(r * 256 + (t & ~63)) * 16);
    }
  };

  stage(0, 0);
  for (int t6 = 0; t6 < K / 64; ++t6) {
    const int cur = t6 & 1;
    if (t6 + 1 < K / 64) {
      stage(cur ^ 1, (t6 + 1) * 64);
      asm volatile("s_waitcnt vmcnt(6)" ::: "memory");
    } else {
      asm volatile("s_waitcnt vmcnt(0)" ::: "memory");
    }
    asm volatile("s_barrier" ::: "memory");

    const char* As = smem + cur * (BM * 128 + 16384);
    const char* Bs = As + BM * 128;
    s16x8 af[2][2], bfr[4][2];
#pragma unroll
    for (int mf = 0; mf < 2; ++mf)
#pragma unroll
      for (int kk = 0; kk < 2; ++kk) {
        int row = wr * 32 + mf * 16 + lr;
        int cb = (lg << 4) + (kk << 6);
        af[mf][kk] = *(const s16x8*)(As + row * 128 + (cb ^ ((row & 7) << 4)));
      }
#pragma unroll
    for (int nf = 0; nf < 4; ++nf)
#pragma unroll
      for (int kk = 0; kk < 2; ++kk) {
        int row = wc * 64 + nf * 16 + lr;
        int cb = (lg << 4) + (kk << 6);
        bfr[nf][kk] = *(const s16x8*)(Bs + row * 128 + (cb ^ ((row & 7) << 4)));
      }
#pragma unroll
    for (int mf = 0; mf < 2; ++mf)
#pragma unroll
      for (int nf = 0; nf < 4; ++nf)
#pragma unroll
        for (int kk = 0; kk < 2; ++kk)
          acc[mf][nf] = mfma16(af[mf][kk], bfr[nf][kk], acc[mf][nf]);

    asm volatile("s_waitcnt lgkmcnt(0)" ::: "memory");
    asm volatile("s_barrier" ::: "memory");
  }

#pragma unroll
  for (int mf = 0; mf < 2; ++mf)
#pragma unroll
    for (int nf = 0; nf < 4; ++nf) {
      int m0 = bm + wr * 32 + mf * 16 + (lg << 2);
      int nc = wc * 64 + nf * 16 + lr;
      float bv = bp[nloc + nc];
      if (mode == 0) {
#pragma unroll
        for (int r = 0; r < 4; ++r)
          outp[(size_t)(m0 + r) * 1024 + nloc + nc] = f2bf((acc[mf][nf][r] + bv) * qsc);
      } else {
        int b = m0 >> 11, s = m0 & 2047;
        u16x4 o;
        o.x = f2bf(acc[mf][nf][0] + bv);
        o.y = f2bf(acc[mf][nf][1] + bv);
        o.z = f2bf(acc[mf][nf][2] + bv);
        o.w = f2bf(acc[mf][nf][3] + bv);
        *(u16x4*)&outp[((size_t)b * NE + nloc + nc) * NS + s] = o;
      }
    }
}

// ---------------- O-projection GEMM (f32 out), BM=64 ----------------
__global__ __launch_bounds__(256, 3) void gemm_o(
    const unsigned short* __restrict__ A, const unsigned short* __restrict__ W,
    const float* __restrict__ bias, float* __restrict__ out) {
  constexpr int BM = 64, K = 1024;
  __shared__ char smem[2 * (BM * 128 + 16384)];
  const int t = threadIdx.x;
  const int lane = t & 63;
  const int wv = t >> 6;
  const int wr = wv >> 1, wc = wv & 1;
  const int bm = blockIdx.y * BM, bn = blockIdx.x * 128;
  const int lr = lane & 15, lg = lane >> 4;

  f32x4 acc[2][4] = {};

  auto stage = [&](int buf, int k0) {
    char* As = smem + buf * (BM * 128 + 16384);
    char* Bs = As + BM * 128;
#pragma unroll
    for (int r = 0; r < 2; ++r) {
      int lin = r * 256 + t;
      int row = lin >> 3;
      int scb = ((lin & 7) << 4) ^ ((row & 7) << 4);
      gload_lds16((const char*)(A + (size_t)(bm + row) * K + k0) + scb,
                  As + (size_t)(r * 256 + (t & ~63)) * 16);
    }
#pragma unroll
    for (int r = 0; r < 4; ++r) {
      int lin = r * 256 + t;
      int row = lin >> 3;
      int scb = ((lin & 7) << 4) ^ ((row & 7) << 4);
      gload_lds16((const char*)(W + (size_t)(bn + row) * K + k0) + scb,
                  Bs + (size_t)(r * 256 + (t & ~63)) * 16);
    }
  };

  stage(0, 0);
  for (int t6 = 0; t6 < K / 64; ++t6) {
    const int cur = t6 & 1;
    if (t6 + 1 < K / 64) {
      stage(cur ^ 1, (t6 + 1) * 64);
      asm volatile("s_waitcnt vmcnt(6)" ::: "memory");
    } else {
      asm volatile("s_waitcnt vmcnt(0)" ::: "memory");
    }
    asm volatile("s_barrier" ::: "memory");

    const char* As = smem + cur * (BM * 128 + 16384);
    const char* Bs = As + BM * 128;
    s16x8 af[2][2], bfr[4][2];
#pragma unroll
    for (int mf = 0; mf < 2; ++mf)
#pragma unroll
      for (int kk = 0; kk < 2; ++kk) {
        int row = wr * 32 + mf * 16 + lr;
        int cb = (lg << 4) + (kk << 6);
        af[mf][kk] = *(const s16x8*)(As + row * 128 + (cb ^ ((row & 7) << 4)));
      }
#pragma unroll
    for (int nf = 0; nf < 4; ++nf)
#pragma unroll
      for (int kk = 0; kk < 2; ++kk) {
        int row = wc * 64 + nf * 16 + lr;
        int cb = (lg << 4) + (kk << 6);
        bfr[nf][kk] = *(const s16x8*)(Bs + row * 128 + (cb ^ ((row & 7) << 4)));
      }
#pragma unroll
    for (int mf = 0; mf < 2; ++mf)
#pragma unroll
      for (int nf = 0; nf < 4; ++nf)
#pragma unroll
        for (int kk = 0; kk < 2; ++kk)
          acc[mf][nf] = mfma16(af[mf][kk], bfr[nf][kk], acc[mf][nf]);

    asm volatile("s_waitcnt lgkmcnt(0)" ::: "memory");
    asm volatile("s_barrier" ::: "memory");
  }

#pragma unroll
  for (int mf = 0; mf < 2; ++mf)
#pragma unroll
    for (int nf = 0; nf < 4; ++nf) {
      int m0 = bm + wr * 32 + mf * 16 + (lg << 2);
      int n = bn + wc * 64 + nf * 16 + lr;
      float bv = bias[n];
#pragma unroll
      for (int r = 0; r < 4; ++r)
        out[(size_t)(m0 + r) * 1024 + n] = acc[mf][nf][r] + bv;
    }
}

// ---------------- Flash attention: 8-wave blocks (QBLK=256), T15 pipeline ----------------
// grid (S/256, B*H), 512 threads = 8 waves; wave owns 32 q-rows.
// Same schedule as round-7 best: static-max softmax, per-iter vmcnt -> barrier ->
// stage(t+2) -> [QK(t)+PV(t-1)] cluster -> smpack(t). 4 LDS buffers.
// 8 waves share each staged 16KB tile -> staging bytes/FLOP and barriers/FLOP halve.
// Per-thread staging: 1 K-load + 1 V-load per tile (512 x 16B = 8KB each).
__global__ __launch_bounds__(512, 2) void attn_fwd(
    const unsigned short* __restrict__ qb, const unsigned short* __restrict__ kb,
    const unsigned short* __restrict__ vt, const unsigned long long* __restrict__ bmw,
    unsigned short* __restrict__ ob) {
  __shared__ char smem[65536];  // 4 bufs x (K 8KB | V 8KB)
  const int t = threadIdx.x, lane = t & 63, wv = t >> 6;
  const int l31 = lane & 31, hi = lane >> 5;
  const int sw = (l31 & 15) << 4;
  const int bh = blockIdx.y, b = bh >> 4, h = bh & 15;
  const int q = blockIdx.x * 256 + wv * 32 + l31;

  // Q fragments (B-operand: col=q=lane&31, k = 16*ks + 8*hi + e); pre-scaled
  s16x8 qf[4];
#pragma unroll
  for (int ks = 0; ks < 4; ++ks)
    qf[ks] = *(const s16x8*)&qb[((size_t)(b * NS + q)) * NE + h * ND + ks * 16 + hi * 8];

  // mask bitmask words: lane i holds word for tile (i&31)
  unsigned long long mword = bmw[(size_t)b * 32 + l31];
  unsigned mlo = (unsigned)mword, mhi = (unsigned)(mword >> 32);

  // staging source addresses (hoisted); inverse-swizzled global src.
  // Single 16B load per thread per K tile (512x16B = 8KB) and per V tile.
  const char* kSrc; const char* vSrc; int ldsB;
  {
    int L = t * 16;
    int row = L >> 8;
    int offp = (L & 255) ^ ((row & 15) << 4);
    int rr = row + ((offp >> 7) << 5);
    int byo = offp & 127;
    kSrc = (const char*)&kb[((size_t)(b * NS) + rr) * NE + h * ND] + byo;
    vSrc = (const char*)&vt[((size_t)((b * NH + h) * ND) + rr) * NS] + byo;
    ldsB = (t & ~63) * 16;  // wave-uniform base; HW adds lane*16
  }

  // frag LDS offsets, shared by K and V
  int off16[8];
#pragma unroll
  for (int j = 0; j < 8; ++j)
    off16[j] = l31 * 256 + ((j * 32 + hi * 16) ^ sw);

  auto stage = [&](int buf, int kt) {
    char* base = smem + buf * 16384;
    gload_lds16(kSrc + (size_t)kt * (NE * 2), base + ldsB);
    gload_lds16(vSrc + (size_t)kt * 2, base + 8192 + ldsB);
  };

  f32x16 oacc[2] = {};
  f32x16 lacc = {};
  s16x8 pfp[4];  // P fragments of tile t-1, carried across iterations

  auto qk = [&](const char* Ks, f32x16& st0, f32x16& st1) {
#pragma unroll
    for (int ks = 0; ks < 4; ++ks) {
      s16x8 kf = *(const s16x8*)(Ks + off16[ks]);
      st0 = mfma32(kf, qf[ks], st0);
    }
#pragma unroll
    for (int ks = 0; ks < 4; ++ks) {
      s16x8 kf = *(const s16x8*)(Ks + off16[4 + ks]);
      st1 = mfma32(kf, qf[ks], st1);
    }
  };

  auto pv = [&](const char* Vs) {
#pragma unroll
    for (int td = 0; td < 2; ++td)
#pragma unroll
      for (int ks = 0; ks < 4; ++ks) {
        s16x8 vf = *(const s16x8*)(Vs + off16[td * 4 + ks]);
        oacc[td] = mfma32(vf, pfp[ks], oacc[td]);
      }
  };

  auto smpack = [&](int tt, f32x16& st0, f32x16& st1) {
    // static-max exp: p = exp2(st - 6)
#pragma unroll
    for (int r = 0; r < 16; ++r) st0[r] = __builtin_amdgcn_exp2f(st0[r] - 6.0f);
#pragma unroll
    for (int r = 0; r < 16; ++r) st1[r] = __builtin_amdgcn_exp2f(st1[r] - 6.0f);

    // mask via prepacked bitmask (fast path: all-ones)
    unsigned lo = (unsigned)__builtin_amdgcn_readlane((int)mlo, tt);
    unsigned hh = (unsigned)__builtin_amdgcn_readlane((int)mhi, tt);
    unsigned long long bal = ((unsigned long long)hh << 32) | lo;
    if (bal != ~0ull) {
#pragma unroll
      for (int r = 0; r < 16; ++r) {
        int key0 = (r & 3) + 8 * (r >> 2) + 4 * hi;
        if (!((bal >> key0) & 1)) st0[r] = 0.f;
        if (!((bal >> (key0 + 32)) & 1)) st1[r] = 0.f;
      }
    }

    lacc += st0;
    lacc += st1;

    // pack P -> PV B-fragments (T12: cvt_pk + permlane32_swap)
#pragma unroll
    for (int ks = 0; ks < 4; ++ks) {
      const int r0 = (ks & 1) * 8;
      unsigned wreg[4];
#pragma unroll
      for (int w = 0; w < 2; ++w) {
        float e0, e1, e2, e3;
        if (ks < 2) {
          e0 = st0[r0 + 2 * w]; e1 = st0[r0 + 2 * w + 1];
          e2 = st0[r0 + 4 + 2 * w]; e3 = st0[r0 + 4 + 2 * w + 1];
        } else {
          e0 = st1[r0 + 2 * w]; e1 = st1[r0 + 2 * w + 1];
          e2 = st1[r0 + 4 + 2 * w]; e3 = st1[r0 + 4 + 2 * w + 1];
        }
        unsigned x = cvtpk_bf16(e0, e1);
        unsigned y = cvtpk_bf16(e2, e3);
        uint2v r2 = __builtin_amdgcn_permlane32_swap(x, y, false, false);
        wreg[w] = r2.x;
        wreg[w + 2] = r2.y;
      }
      union { unsigned u[4]; s16x8 v; } pu;
      pu.u[0] = wreg[0]; pu.u[1] = wreg[1]; pu.u[2] = wreg[2]; pu.u[3] = wreg[3];
      pfp[ks] = pu.v;
    }
  };

  stage(0, 0);
  stage(1, 64);

  // peel tile 0: QK + softmax only
  asm volatile("s_waitcnt vmcnt(2)" ::: "memory");  // stage(0)'s 2 loads done
  __builtin_amdgcn_s_barrier();
  stage(2, 128);
  {
    f32x16 s0 = {}, s1 = {};
    __builtin_amdgcn_s_setprio(1);
    qk(smem, s0, s1);
    __builtin_amdgcn_s_setprio(0);
    smpack(0, s0, s1);
  }

#pragma unroll 1
  for (int tt = 1; tt < NT; ++tt) {
    if (tt + 1 < NT) {
      asm volatile("s_waitcnt vmcnt(2)" ::: "memory");  // stage(tt) done, stage(tt+1) in flight
    } else {
      asm volatile("s_waitcnt vmcnt(0)" ::: "memory");
    }
    __builtin_amdgcn_s_barrier();
    if (tt + 2 < NT) stage((tt + 2) & 3, (tt + 2) * 64);

    const char* Kb = smem + (tt & 3) * 16384;
    const char* Vb = smem + ((tt - 1) & 3) * 16384 + 8192;
    f32x16 s0 = {}, s1 = {};
    __builtin_amdgcn_s_setprio(1);
    qk(Kb, s0, s1);   // QK(t)
    pv(Vb);           // PV(t-1) — same MFMA cluster
    __builtin_amdgcn_s_setprio(0);
    smpack(tt, s0, s1);
  }

  // final PV(NT-1); its V buffer (buf3 V area) is untouched by the epilogue
  __builtin_amdgcn_s_setprio(1);
  pv(smem + ((NT - 1) & 3) * 16384 + 8192);
  __builtin_amdgcn_s_setprio(0);

  // epilogue: l = tree(lacc) + cross-half; normalize, LDS transpose, store
  float l0 = 0.f;
#pragma unroll
  for (int r = 0; r < 16; ++r) l0 += lacc[r];
  float l = l0 + __shfl_xor(l0, 32);
  float inv = 1.0f / l;

  // per-wave 4KB regions: waves 0-7 use [0, 32768) = buf0+buf1; all loop reads
  // after the last barrier touch only buf2 V / buf3 (disjoint) -> no barrier.
  char* Ob = smem + wv * 4096;
#pragma unroll
  for (int td = 0; td < 2; ++td)
#pragma unroll
    for (int i = 0; i < 8; ++i) {
      int r = 2 * i;
      int d = td * 32 + (r & 3) + 8 * (r >> 2) + 4 * hi;
      unsigned pk = cvtpk_bf16(oacc[td][r] * inv, oacc[td][r + 1] * inv);
      *(unsigned*)(Ob + l31 * 128 + ((d * 2) ^ ((l31 & 7) << 4))) = pk;
    }
#pragma unroll
  for (int p4 = 0; p4 < 4; ++p4) {
    int lq = p4 * 8 + (lane >> 3);
    int col = (lane & 7) * 16;
    s16x8 v0 = *(const s16x8*)(Ob + lq * 128 + (col ^ ((lq & 7) << 4)));
    int qg = blockIdx.x * 256 + wv * 32 + lq;
    *(s16x8*)((char*)&ob[((size_t)(b * NS + qg)) * NE + h * ND] + col) = v0;
  }
}

// ---------------- launch ----------------
extern "C" void kernel_launch(void* const* d_in, const int* in_sizes, int n_in,
                              void* d_out, int out_size, void* d_ws, size_t ws_size,
                              hipStream_t stream) {
  const float* queries = (const float*)d_in[0];
  const float* keys = (const float*)d_in[1];
  // d_in[2] (values) is unused by the reference
  const int* mask = (const int*)d_in[3];
  const float* Wq = (const float*)d_in[4];
  const float* bq = (const float*)d_in[5];
  const float* Wk = (const float*)d_in[6];
  const float* bk = (const float*)d_in[7];
  const float* Wv = (const float*)d_in[8];
  const float* bv = (const float*)d_in[9];
  const float* Wo = (const float*)d_in[10];
  const float* bo = (const float*)d_in[11];
  float* out = (float*)d_out;

  char* ws = (char*)d_ws;
  const size_t SZ_X = (size_t)NB * NS * NE * 2;  // 8 MiB
  const size_t SZ_W = (size_t)NE * NE * 2;       // 2 MiB
  unsigned short* qbf = (unsigned short*)(ws);
  unsigned short* kbf = (unsigned short*)(ws + SZ_X);
  unsigned short* wqb = (unsigned short*)(ws + 2 * SZ_X);
  unsigned short* wkb = (unsigned short*)(ws + 2 * SZ_X + SZ_W);
  unsigned short* wvb = (unsigned short*)(ws + 2 * SZ_X + 2 * SZ_W);
  unsigned short* wob = (unsigned short*)(ws + 2 * SZ_X + 3 * SZ_W);
  unsigned short* qp  = (unsigned short*)(ws + 2 * SZ_X + 4 * SZ_W);
  unsigned short* kp  = (unsigned short*)(ws + 3 * SZ_X + 4 * SZ_W);
  unsigned short* vtp = (unsigned short*)(ws + 4 * SZ_X + 4 * SZ_W);
  unsigned short* ao  = (unsigned short*)(ws + 5 * SZ_X + 4 * SZ_W);
  unsigned long long* bmp = (unsigned long long*)(ws + 6 * SZ_X + 4 * SZ_W);

  // fused prologue: converts + mask pack (1 launch)
  prep<<<3088, 256, 0, stream>>>(queries, keys, qbf, kbf,
                                 Wq, Wk, Wv, Wo, wqb, wkb, wvb, wob,
                                 mask, bmp);

  // fused Q + K + V projections (BM=64; Q pre-scaled by 0.125*log2e)
  gemm_qkv<<<dim3(24, 64), 256, 0, stream>>>(qbf, kbf, wqb, wkb, wvb,
                                             bq, bk, bv, qp, kp, vtp);

  dim3 ga(NS / 256, NB * NH);  // (8, 32) = 256 blocks x 512 threads
  attn_fwd<<<ga, 512, 0, stream>>>(qp, kp, vtp, bmp, ao);

  // output projection: f32 out
  gemm_o<<<dim3(8, 64), 256, 0, stream>>>(ao, wob, bo, out);
}